// Round 2
// baseline (197.806 us; speedup 1.0000x reference)
//
#include <hip/hip_runtime.h>
#include <hip/hip_bf16.h>
#include <cmath>

typedef __hip_bfloat16 bf16;
typedef short v8s __attribute__((ext_vector_type(8)));   // 8 x bf16 bits
typedef short v4s __attribute__((ext_vector_type(4)));   // 4 x bf16 bits
typedef float v4f __attribute__((ext_vector_type(4)));
typedef float v16f __attribute__((ext_vector_type(16)));
typedef unsigned v4u __attribute__((ext_vector_type(4)));

#define AS1(p) ((__attribute__((address_space(1))) void*)(p))
#define AS3(p) ((__attribute__((address_space(3))) void*)(p))

__device__ __forceinline__ v4f mfma_bf16(v8s a, v8s b, v4f c) {
    return __builtin_amdgcn_mfma_f32_16x16x32_bf16(a, b, c, 0, 0, 0);
}
__device__ __forceinline__ v16f mfma32(v8s a, v8s b, v16f c) {
    return __builtin_amdgcn_mfma_f32_32x32x16_bf16(a, b, c, 0, 0, 0);
}

__device__ __forceinline__ short bf16_bits(float f) {
    return __builtin_bit_cast(short, __float2bfloat16(f));
}

__device__ __forceinline__ v8s pack4(unsigned a, unsigned b, unsigned c, unsigned d) {
    v4u u = {a, b, c, d};
    return __builtin_bit_cast(v8s, u);
}

// fused fp32 -> bf16 for x, w_in, w_out (float4 granularity)
__global__ __launch_bounds__(256)
void cvt_all(const float* __restrict__ x, const float* __restrict__ w_in,
             const float* __restrict__ w_out, bf16* __restrict__ xb,
             bf16* __restrict__ wib, bf16* __restrict__ wob)
{
    const int i = blockIdx.x * 256 + threadIdx.x;   // 0 .. 2097151
    const float* src; bf16* dst; int j;
    if (i < 1048576)      { src = x;     dst = xb;  j = i; }
    else if (i < 1835008) { src = w_in;  dst = wib; j = i - 1048576; }
    else                  { src = w_out; dst = wob; j = i - 1835008; }
    const float4 v = ((const float4*)src)[j];
    v4s p;
    p.x = bf16_bits(v.x); p.y = bf16_bits(v.y);
    p.z = bf16_bits(v.z); p.w = bf16_bits(v.w);
    ((v4s*)dst)[j] = p;
}

// C[m,n] = sum_k A[m,k] * Bt[n,k] + bias[n].  Tile: 128 x (NF*32), BK=32,
// DOUBLE-BUFFERED: next K-tile's global_load_lds issued right after the single
// per-iteration barrier, so the barrier drain covers loads issued one full
// compute phase earlier (attn-proven structure).
// XOR-4 swizzle on 64B LDS rows: store chunk (t&3)^((row>>1)&3), read chunk
// quad^((l16>>1)&3) -> every (row-parity x chunk) bank group gets exactly
// 2 lanes = conflict-free. Staging keeps contiguous t*16 LDS dst.
template<int NF>
__global__ __launch_bounds__(256)
void gemm_bt(const bf16* __restrict__ A, const bf16* __restrict__ Bt,
             const float* __restrict__ bias, bf16* __restrict__ C,
             float* __restrict__ Cf, int N, int K, int lda)
{
    constexpr int BN = NF * 32;
    __shared__ __align__(16) bf16 As[2][128 * 32];
    __shared__ __align__(16) bf16 Bs[2][BN * 32];

    const int t    = threadIdx.x;
    const int lane = t & 63;
    const int wave = t >> 6;
    const int l16  = lane & 15;
    const int quad = lane >> 4;
    const int m0   = blockIdx.y * 128;
    const int n0   = blockIdx.x * BN;
    const int wm   = (wave >> 1) * 64;        // 2x2 wave grid
    const int wn   = (wave & 1) * (NF * 16);

    const v4f zf = {0.f, 0.f, 0.f, 0.f};
    v4f acc[4][NF];
#pragma unroll
    for (int i = 0; i < 4; ++i)
#pragma unroll
        for (int j = 0; j < NF; ++j) acc[i][j] = zf;

    // staging: thread t loads 16B; row sr = t>>2 (+64 for 2nd A-half),
    // global chunk g = (t&3) ^ ((sr>>1)&3)
    const int sr = t >> 2;
    const int g  = ((t & 3) ^ ((sr >> 1) & 3)) * 8;
    const bf16* gA = A  + (size_t)(m0 + sr) * lda + g;
    const bf16* gB = Bt + (size_t)(n0 + sr) * K + g;

    auto stage = [&](int kt, int buf) {
        const int k0 = kt * 32;
        char* lA = (char*)&As[buf][0] + t * 16;
        char* lB = (char*)&Bs[buf][0] + t * 16;
        __builtin_amdgcn_global_load_lds(AS1(gA + k0),                    AS3(lA),        16, 0, 0);
        __builtin_amdgcn_global_load_lds(AS1(gA + (size_t)64 * lda + k0), AS3(lA + 4096), 16, 0, 0);
        __builtin_amdgcn_global_load_lds(AS1(gB + k0),                    AS3(lB),        16, 0, 0);
        if (NF == 4)
            __builtin_amdgcn_global_load_lds(AS1(gB + (size_t)64 * K + k0), AS3(lB + 4096), 16, 0, 0);
    };

    stage(0, 0);
    const int KT = K >> 5;
    const int xs = ((l16 >> 1) & 3) * 8;   // read-side chunk swizzle
    for (int kt = 0; kt < KT; ++kt) {
        const int buf = kt & 1;
        __syncthreads();                    // buf staged; prev reads of buf^1 done
        if (kt + 1 < KT) stage(kt + 1, buf ^ 1);

        v8s af[4], bfr[NF];
#pragma unroll
        for (int mi = 0; mi < 4; ++mi)
            af[mi] = *(const v8s*)(&As[buf][0] + (wm + mi * 16 + l16) * 32
                                   + ((quad * 8) ^ xs));
#pragma unroll
        for (int ni = 0; ni < NF; ++ni)
            bfr[ni] = *(const v8s*)(&Bs[buf][0] + (wn + ni * 16 + l16) * 32
                                    + ((quad * 8) ^ xs));
#pragma unroll
        for (int mi = 0; mi < 4; ++mi)
#pragma unroll
            for (int ni = 0; ni < NF; ++ni)
                acc[mi][ni] = mfma_bf16(af[mi], bfr[ni], acc[mi][ni]);
    }

    // epilogue: D[row=quad*4+r][col=l16] per 16x16 tile (m91-verified layout)
#pragma unroll
    for (int ni = 0; ni < NF; ++ni) {
        const int col = n0 + wn + ni * 16 + l16;
        const float bv = bias[col];
#pragma unroll
        for (int mi = 0; mi < 4; ++mi) {
#pragma unroll
            for (int r = 0; r < 4; ++r) {
                const int row = m0 + wm + mi * 16 + quad * 4 + r;
                const float fv = acc[mi][ni][r] + bv;
                if (Cf) Cf[(size_t)row * N + col] = fv;
                else    C [(size_t)row * N + col] = __float2bfloat16(fv);
            }
        }
    }
}

// V transpose: qkv V-third [b][s][h*64+d] -> Vt[(b*16+h)][d][s]  (64x64 LDS tiles)
__global__ __launch_bounds__(256)
void vtrans(const bf16* __restrict__ qkv, bf16* __restrict__ Vt)
{
    __shared__ short Ts[64][72];
    const int t  = threadIdx.x;
    const int st = blockIdx.x;     // s-tile 0..31
    const int bh = blockIdx.y;     // 0..31
    const int b = bh >> 4, h = bh & 15;
    const int s0 = st * 64;
    {
        const int i = t >> 2, j0 = (t & 3) * 16;
        const bf16* src = qkv + (size_t)(b * 2048 + s0 + i) * 3072 + 2048 + h * 64 + j0;
        const v8s a0 = *(const v8s*)(src);
        const v8s a1 = *(const v8s*)(src + 8);
        *(v8s*)&Ts[i][j0]     = a0;
        *(v8s*)&Ts[i][j0 + 8] = a1;
    }
    __syncthreads();
    {
        const int d = t >> 2, seg = (t & 3) * 16;
        v8s o0, o1;
#pragma unroll
        for (int m = 0; m < 8; ++m) { o0[m] = Ts[seg + m][d]; o1[m] = Ts[seg + 8 + m][d]; }
        bf16* dst = Vt + (size_t)(bh * 64 + d) * 2048 + s0 + seg;
        *(v8s*)dst       = o0;
        *(v8s*)(dst + 8) = o1;
    }
}

// Block-cooperative causal flash attention, 64 q-rows/block, 2 waves x 32 rows,
// 32x32x16 MFMA with SWAPPED QK^T (S^T = K*Q^T) so each lane owns a full P row
// (q = lane&31, k = crow(r,hi)) -> in-register softmax, NO P LDS round-trip.
// P -> PV A-fragment via v_cvt_pk_bf16_f32 + v_permlane32_swap (T12 recipe).
// K/V tiles (64) double-buffered via global_load_lds prefetch, ONE barrier/tile.
// XOR-8 swizzled LDS rows (128B). Static-max softmax p = exp(s/8 - 14).
#define M_STATIC 14.0f

__device__ __forceinline__ void softpack(v16f s, int kg0, int qg, bool mask, int hi,
                                         float& lsum, v8s& paE, v8s& paO)
{
    float p[16];
#pragma unroll
    for (int r = 0; r < 16; ++r) {
        float pv = __expf(fmaf(s[r], 0.125f, -M_STATIC));
        if (mask) {
            const int kg = kg0 + (r & 3) + 8 * (r >> 2) + 4 * hi;
            if (kg > qg) pv = 0.f;
        }
        lsum += pv;
        p[r] = pv;
    }
    unsigned P0[4], P1[4];
#pragma unroll
    for (int m = 0; m < 4; ++m) {
        asm("v_cvt_pk_bf16_f32 %0, %1, %2" : "=v"(P0[m]) : "v"(p[4 * m]),     "v"(p[4 * m + 1]));
        asm("v_cvt_pk_bf16_f32 %0, %1, %2" : "=v"(P1[m]) : "v"(p[4 * m + 2]), "v"(p[4 * m + 3]));
    }
    // lane h needs k = 8h..8h+7 (paE) / 16+8h..+7 (paO); partner half comes via swap
    auto sA = __builtin_amdgcn_permlane32_swap(P0[0], P0[1], false, false);
    auto sB = __builtin_amdgcn_permlane32_swap(P1[0], P1[1], false, false);
    auto sC = __builtin_amdgcn_permlane32_swap(P0[2], P0[3], false, false);
    auto sD = __builtin_amdgcn_permlane32_swap(P1[2], P1[3], false, false);
    paE = pack4(sA[0], sB[0], sA[1], sB[1]);
    paO = pack4(sC[0], sD[0], sC[1], sD[1]);
}

__global__ __launch_bounds__(128)
void attn(bf16* __restrict__ qkv, const bf16* __restrict__ Vt)
{
    __shared__ __align__(16) bf16 Ks[2][64 * 64];   // [krow][d-chunk swizzled]
    __shared__ __align__(16) bf16 Vs[2][64 * 64];   // [d][s-chunk swizzled]

    const int t    = threadIdx.x;        // 0..127
    const int lane = t & 63;
    const int w    = t >> 6;             // wave 0,1
    const int l31  = lane & 31;
    const int hi   = lane >> 5;
    const int id   = blockIdx.x;         // 1024 blocks
    const int bh   = id & 31;
    const int qb   = 31 - (id >> 5);     // heavy-first: qb 31..0
    const int b = bh >> 4, h = bh & 15;
    const int T = qb + 1;                // 64-wide k-tiles to the causal frontier
    const int rowq = qb * 64 + w * 32;   // wave's first q-row
    const int qg   = rowq + l31;         // this lane's q row (S^T col)
    const int xr   = l31 & 7;            // read-side chunk swizzle

    // Q fragments (B-operand rows): qf[c] = Q[qg][16c + 8hi + j]
    v8s qf[4];
    {
        const bf16* Qb = qkv + (size_t)(b * 2048 + qg) * 3072 + h * 64 + hi * 8;
#pragma unroll
        for (int c = 0; c < 4; ++c) qf[c] = *(const v8s*)(Qb + c * 16);
    }

    // staging: thread t fetches 16B; LDS dst = t*16 (+i*2048); global chunk = c ^ (row&7)
    const int sr  = t >> 3;          // row 0..15 within quarter-tile
    const int swz = ((t & 7) ^ (sr & 7)) * 8;
    const bf16* kbase = qkv + (size_t)(b * 2048 + sr) * 3072 + 1024 + h * 64 + swz;
    const bf16* vbase = Vt + (size_t)(bh * 64 + sr) * 2048 + swz;

    auto stage = [&](int tile, int buf2) {
        char* kd = (char*)&Ks[buf2][0] + t * 16;
        char* vd = (char*)&Vs[buf2][0] + t * 16;
        const bf16* ks0 = kbase + (size_t)(tile * 64) * 3072;
        const bf16* vs0 = vbase + tile * 64;
#pragma unroll
        for (int i = 0; i < 4; ++i) {
            __builtin_amdgcn_global_load_lds(AS1(ks0 + (size_t)(16 * i) * 3072), AS3(kd + i * 2048), 16, 0, 0);
            __builtin_amdgcn_global_load_lds(AS1(vs0 + (size_t)(16 * i) * 2048), AS3(vd + i * 2048), 16, 0, 0);
        }
    };

    stage(0, 0);

    v16f o0 = {}, o1 = {};
    float lsum = 0.f;

    for (int tile = 0; tile < T; ++tile) {
        const int buf = tile & 1;
        __syncthreads();                 // staging of `tile` complete; prior reads done
        if (tile + 1 < T) stage(tile + 1, buf ^ 1);

        const bf16* Kb = &Ks[buf][0];
        const bf16* Vb = &Vs[buf][0];
        const bool last = (tile == T - 1);
        const bool do1  = (!last) || (w == 1);   // wave 0's k 32..63 on diag is all-masked

        // QK^T swapped: s = mfma(K rows, Q rows) -> S^T[k][q], lane: q=l31, k=crow(r,hi)
        v16f s0 = {}, s1 = {};
#pragma unroll
        for (int c = 0; c < 4; ++c) {
            const v8s kf = *(const v8s*)(Kb + l31 * 64 + (((2 * c + hi) ^ xr) * 8));
            s0 = mfma32(kf, qf[c], s0);
        }
        if (do1) {
#pragma unroll
            for (int c = 0; c < 4; ++c) {
                const v8s kf = *(const v8s*)(Kb + (32 + l31) * 64 + (((2 * c + hi) ^ xr) * 8));
                s1 = mfma32(kf, qf[c], s1);
            }
        }

        v8s pa0, pa1, pa2, pa3;
        softpack(s0, tile * 64,      qg, last, hi, lsum, pa0, pa1);
        if (do1) softpack(s1, tile * 64 + 32, qg, last, hi, lsum, pa2, pa3);

        // PV: O[q][d] += P[q][k] V[k][d]; vf(dsub,ks) = V[16ks+8hi+j][32dsub+l31]
        o0 = mfma32(pa0, *(const v8s*)(Vb + l31 * 64        + (((0 + hi) ^ xr) * 8)), o0);
        o1 = mfma32(pa0, *(const v8s*)(Vb + (32 + l31) * 64 + (((0 + hi) ^ xr) * 8)), o1);
        o0 = mfma32(pa1, *(const v8s*)(Vb + l31 * 64        + (((2 + hi) ^ xr) * 8)), o0);
        o1 = mfma32(pa1, *(const v8s*)(Vb + (32 + l31) * 64 + (((2 + hi) ^ xr) * 8)), o1);
        if (do1) {
            o0 = mfma32(pa2, *(const v8s*)(Vb + l31 * 64        + (((4 + hi) ^ xr) * 8)), o0);
            o1 = mfma32(pa2, *(const v8s*)(Vb + (32 + l31) * 64 + (((4 + hi) ^ xr) * 8)), o1);
            o0 = mfma32(pa3, *(const v8s*)(Vb + l31 * 64        + (((6 + hi) ^ xr) * 8)), o0);
            o1 = mfma32(pa3, *(const v8s*)(Vb + (32 + l31) * 64 + (((6 + hi) ^ xr) * 8)), o1);
        }
    }

    // full row sum: own-hi partial + partner half, then broadcast per output row
    const float lt = lsum + __shfl_xor(lsum, 32);

    // write attention output into the dead V-third of qkv (cols 2048+)
    bf16* dst0 = qkv + (size_t)(b * 2048 + rowq) * 3072 + 2048 + h * 64 + l31;
#pragma unroll
    for (int r = 0; r < 16; ++r) {
        const int q = (r & 3) + 8 * (r >> 2) + 4 * hi;   // O row for this reg
        const float rs  = fmaxf(__shfl(lt, q), 1e-30f);
        const float inv = 1.0f / rs;
        bf16* dst = dst0 + (size_t)q * 3072;
        dst[0]  = __float2bfloat16(o0[r] * inv);
        dst[32] = __float2bfloat16(o1[r] * inv);
    }
}

extern "C" void kernel_launch(void* const* d_in, const int* in_sizes, int n_in,
                              void* d_out, int out_size, void* d_ws, size_t ws_size,
                              hipStream_t stream)
{
    (void)in_sizes; (void)n_in; (void)out_size; (void)ws_size;
    const float* x     = (const float*)d_in[0];
    const float* w_in  = (const float*)d_in[1];
    const float* b_in  = (const float*)d_in[2];
    const float* w_out = (const float*)d_in[3];
    const float* b_out = (const float*)d_in[4];
    float* out = (float*)d_out;   // fp32 output [4096][1024]

    bf16* ws     = (bf16*)d_ws;
    bf16* xb     = ws;                           // [4096][1024]   8.4 MB
    bf16* w_inb  = xb     + (size_t)4096 * 1024; // [3072][1024]   6.3 MB
    bf16* w_outb = w_inb  + (size_t)3072 * 1024; // [1024][1024]   2.1 MB
    bf16* qkv    = w_outb + (size_t)1024 * 1024; // [4096][3072]  25.2 MB
    bf16* vt     = (bf16*)d_out;                 // [32*64][2048] scratch in d_out
                                                 // (dead before final GEMM writes out)

    cvt_all<<<8192, 256, 0, stream>>>(x, w_in, w_out, xb, w_inb, w_outb);

    // QKV projection: x[4096,1024] @ w_in^T + b_in -> qkv (128x128, BK=32, dbuf)
    gemm_bt<4><<<dim3(24, 32), dim3(256), 0, stream>>>(xb, w_inb, b_in, qkv, nullptr,
                                                       3072, 1024, 1024);
    // V -> Vt[bh][d][s]
    vtrans<<<dim3(32, 32), dim3(256), 0, stream>>>(qkv, vt);
    // causal flash attention (2-wave blocks, 32x32 MFMA, in-register softmax)
    attn<<<1024, 128, 0, stream>>>(qkv, vt);
    // output projection -> fp32 d_out (128x64 tiles: 512 blocks = 2/CU)
    gemm_bt<2><<<dim3(16, 32), dim3(256), 0, stream>>>(qkv + 2048, w_outb, b_out, nullptr,
                                                       out, 1024, 1024, 3072);
}

// Round 3
// 196.865 us; speedup vs baseline: 1.0048x; 1.0048x over previous
//
#include <hip/hip_runtime.h>
#include <hip/hip_bf16.h>
#include <cmath>

typedef __hip_bfloat16 bf16;
typedef short v8s __attribute__((ext_vector_type(8)));   // 8 x bf16 bits
typedef short v4s __attribute__((ext_vector_type(4)));   // 4 x bf16 bits
typedef float v4f __attribute__((ext_vector_type(4)));
typedef float v16f __attribute__((ext_vector_type(16)));
typedef unsigned v4u __attribute__((ext_vector_type(4)));

#define AS1(p) ((__attribute__((address_space(1))) void*)(p))
#define AS3(p) ((__attribute__((address_space(3))) void*)(p))

__device__ __forceinline__ v4f mfma_bf16(v8s a, v8s b, v4f c) {
    return __builtin_amdgcn_mfma_f32_16x16x32_bf16(a, b, c, 0, 0, 0);
}
__device__ __forceinline__ v16f mfma32(v8s a, v8s b, v16f c) {
    return __builtin_amdgcn_mfma_f32_32x32x16_bf16(a, b, c, 0, 0, 0);
}

__device__ __forceinline__ short bf16_bits(float f) {
    return __builtin_bit_cast(short, __float2bfloat16(f));
}

__device__ __forceinline__ v8s pack4(unsigned a, unsigned b, unsigned c, unsigned d) {
    v4u u = {a, b, c, d};
    return __builtin_bit_cast(v8s, u);
}

// fused fp32 -> bf16 for x, w_in, w_out (float4 granularity)
__global__ __launch_bounds__(256)
void cvt_all(const float* __restrict__ x, const float* __restrict__ w_in,
             const float* __restrict__ w_out, bf16* __restrict__ xb,
             bf16* __restrict__ wib, bf16* __restrict__ wob)
{
    const int i = blockIdx.x * 256 + threadIdx.x;   // 0 .. 2097151
    const float* src; bf16* dst; int j;
    if (i < 1048576)      { src = x;     dst = xb;  j = i; }
    else if (i < 1835008) { src = w_in;  dst = wib; j = i - 1048576; }
    else                  { src = w_out; dst = wob; j = i - 1835008; }
    const float4 v = ((const float4*)src)[j];
    v4s p;
    p.x = bf16_bits(v.x); p.y = bf16_bits(v.y);
    p.z = bf16_bits(v.z); p.w = bf16_bits(v.w);
    ((v4s*)dst)[j] = p;
}

// C[m,n] = sum_k A[m,k] * Bt[n,k] + bias[n].  Tile: 128 x (NF*32), BK=32,
// double-buffered global_load_lds, XOR-4 swizzle (proven structure, unchanged).
template<int NF>
__global__ __launch_bounds__(256)
void gemm_bt(const bf16* __restrict__ A, const bf16* __restrict__ Bt,
             const float* __restrict__ bias, bf16* __restrict__ C,
             float* __restrict__ Cf, int N, int K, int lda)
{
    constexpr int BN = NF * 32;
    __shared__ __align__(16) bf16 As[2][128 * 32];
    __shared__ __align__(16) bf16 Bs[2][BN * 32];

    const int t    = threadIdx.x;
    const int lane = t & 63;
    const int wave = t >> 6;
    const int l16  = lane & 15;
    const int quad = lane >> 4;
    const int m0   = blockIdx.y * 128;
    const int n0   = blockIdx.x * BN;
    const int wm   = (wave >> 1) * 64;        // 2x2 wave grid
    const int wn   = (wave & 1) * (NF * 16);

    const v4f zf = {0.f, 0.f, 0.f, 0.f};
    v4f acc[4][NF];
#pragma unroll
    for (int i = 0; i < 4; ++i)
#pragma unroll
        for (int j = 0; j < NF; ++j) acc[i][j] = zf;

    const int sr = t >> 2;
    const int g  = ((t & 3) ^ ((sr >> 1) & 3)) * 8;
    const bf16* gA = A  + (size_t)(m0 + sr) * lda + g;
    const bf16* gB = Bt + (size_t)(n0 + sr) * K + g;

    auto stage = [&](int kt, int buf) {
        const int k0 = kt * 32;
        char* lA = (char*)&As[buf][0] + t * 16;
        char* lB = (char*)&Bs[buf][0] + t * 16;
        __builtin_amdgcn_global_load_lds(AS1(gA + k0),                    AS3(lA),        16, 0, 0);
        __builtin_amdgcn_global_load_lds(AS1(gA + (size_t)64 * lda + k0), AS3(lA + 4096), 16, 0, 0);
        __builtin_amdgcn_global_load_lds(AS1(gB + k0),                    AS3(lB),        16, 0, 0);
        if (NF == 4)
            __builtin_amdgcn_global_load_lds(AS1(gB + (size_t)64 * K + k0), AS3(lB + 4096), 16, 0, 0);
    };

    stage(0, 0);
    const int KT = K >> 5;
    const int xs = ((l16 >> 1) & 3) * 8;   // read-side chunk swizzle
    for (int kt = 0; kt < KT; ++kt) {
        const int buf = kt & 1;
        __syncthreads();
        if (kt + 1 < KT) stage(kt + 1, buf ^ 1);

        v8s af[4], bfr[NF];
#pragma unroll
        for (int mi = 0; mi < 4; ++mi)
            af[mi] = *(const v8s*)(&As[buf][0] + (wm + mi * 16 + l16) * 32
                                   + ((quad * 8) ^ xs));
#pragma unroll
        for (int ni = 0; ni < NF; ++ni)
            bfr[ni] = *(const v8s*)(&Bs[buf][0] + (wn + ni * 16 + l16) * 32
                                    + ((quad * 8) ^ xs));
#pragma unroll
        for (int mi = 0; mi < 4; ++mi)
#pragma unroll
            for (int ni = 0; ni < NF; ++ni)
                acc[mi][ni] = mfma_bf16(af[mi], bfr[ni], acc[mi][ni]);
    }

#pragma unroll
    for (int ni = 0; ni < NF; ++ni) {
        const int col = n0 + wn + ni * 16 + l16;
        const float bv = bias[col];
#pragma unroll
        for (int mi = 0; mi < 4; ++mi) {
#pragma unroll
            for (int r = 0; r < 4; ++r) {
                const int row = m0 + wm + mi * 16 + quad * 4 + r;
                const float fv = acc[mi][ni][r] + bv;
                if (Cf) Cf[(size_t)row * N + col] = fv;
                else    C [(size_t)row * N + col] = __float2bfloat16(fv);
            }
        }
    }
}

// V transpose: qkv V-third [b][s][h*64+d] -> Vt[(b*16+h)][d][s]  (64x64 LDS tiles)
__global__ __launch_bounds__(256)
void vtrans(const bf16* __restrict__ qkv, bf16* __restrict__ Vt)
{
    __shared__ short Ts[64][72];
    const int t  = threadIdx.x;
    const int st = blockIdx.x;     // s-tile 0..31
    const int bh = blockIdx.y;     // 0..31
    const int b = bh >> 4, h = bh & 15;
    const int s0 = st * 64;
    {
        const int i = t >> 2, j0 = (t & 3) * 16;
        const bf16* src = qkv + (size_t)(b * 2048 + s0 + i) * 3072 + 2048 + h * 64 + j0;
        const v8s a0 = *(const v8s*)(src);
        const v8s a1 = *(const v8s*)(src + 8);
        *(v8s*)&Ts[i][j0]     = a0;
        *(v8s*)&Ts[i][j0 + 8] = a1;
    }
    __syncthreads();
    {
        const int d = t >> 2, seg = (t & 3) * 16;
        v8s o0, o1;
#pragma unroll
        for (int m = 0; m < 8; ++m) { o0[m] = Ts[seg + m][d]; o1[m] = Ts[seg + 8 + m][d]; }
        bf16* dst = Vt + (size_t)(bh * 64 + d) * 2048 + s0 + seg;
        *(v8s*)dst       = o0;
        *(v8s*)(dst + 8) = o1;
    }
}

// Causal flash attention: 64 q-rows/block, 4 waves = (2 q-halves) x (2 k-halves),
// 32x32x16 MFMA, swapped QK^T (S^T = K*Q^T), in-register softmax (T12:
// cvt_pk_bf16 + permlane32_swap), static-max p = exp(s/8 - 14).
// FRAGMENT-ORDERED LDS: K/V staged so every MFMA fragment read is
// base + const + lane*16 (identical to the stage-write pattern -> zero bank
// conflicts by construction). K slot (rb*4+c)*64+lane holds K[rb*32+l31][d-chunk
// 2c+hi]; V slot (dsub*4+kp)*64+lane holds V[dsub*32+l31 (=d)][s-chunk 2kp+hi].
// k-split partial O/lsum combined through LDS once per block at the end.
#define M_STATIC 14.0f

__device__ __forceinline__ void softpack(v16f s, int kg0, int qg, bool mask, int hi,
                                         float& lsum, v8s& paE, v8s& paO)
{
    float p[16];
#pragma unroll
    for (int r = 0; r < 16; ++r) {
        float pv = __expf(fmaf(s[r], 0.125f, -M_STATIC));
        if (mask) {
            const int kg = kg0 + (r & 3) + 8 * (r >> 2) + 4 * hi;
            if (kg > qg) pv = 0.f;
        }
        lsum += pv;
        p[r] = pv;
    }
    unsigned P0[4], P1[4];
#pragma unroll
    for (int m = 0; m < 4; ++m) {
        asm("v_cvt_pk_bf16_f32 %0, %1, %2" : "=v"(P0[m]) : "v"(p[4 * m]),     "v"(p[4 * m + 1]));
        asm("v_cvt_pk_bf16_f32 %0, %1, %2" : "=v"(P1[m]) : "v"(p[4 * m + 2]), "v"(p[4 * m + 3]));
    }
    auto sA = __builtin_amdgcn_permlane32_swap(P0[0], P0[1], false, false);
    auto sB = __builtin_amdgcn_permlane32_swap(P1[0], P1[1], false, false);
    auto sC = __builtin_amdgcn_permlane32_swap(P0[2], P0[3], false, false);
    auto sD = __builtin_amdgcn_permlane32_swap(P1[2], P1[3], false, false);
    paE = pack4(sA[0], sB[0], sA[1], sB[1]);
    paO = pack4(sC[0], sD[0], sC[1], sD[1]);
}

__global__ __launch_bounds__(256, 4)
void attn(bf16* __restrict__ qkv, const bf16* __restrict__ Vt)
{
    __shared__ __align__(16) bf16 Ks[2][64 * 64];   // fragment-ordered, 8KB each
    __shared__ __align__(16) bf16 Vs[2][64 * 64];

    const int t    = threadIdx.x;        // 0..255
    const int lane = t & 63;
    const int w    = t >> 6;             // 0..3
    const int wq   = w >> 1;             // q-half
    const int wk   = w & 1;              // k-half
    const int l31  = lane & 31;
    const int hi   = lane >> 5;
    const int id   = blockIdx.x;         // 1024 blocks
    const int bh   = id & 31;
    const int qb   = 31 - (id >> 5);     // heavy-first
    const int b = bh >> 4, h = bh & 15;
    const int T = qb + 1;                // 64-wide k-tiles to the causal frontier
    const int rowq  = qb * 64 + wq * 32; // wave's first q-row
    const int qg    = rowq + l31;        // this lane's q row
    const int ndiag = 2 * qb + wq;       // wave diagonal index (32-units)

    // Q fragments (B-operand): qf[c] = Q[qg][16c + 8hi + j]
    v8s qf[4];
    {
        const bf16* Qb = qkv + (size_t)(b * 2048 + qg) * 3072 + h * 64 + hi * 8;
#pragma unroll
        for (int c = 0; c < 4; ++c) qf[c] = *(const v8s*)(Qb + c * 16);
    }

    // fragment-order staging: thread t owns slots t and t+256.
    // slot decode: row-in-32 = t&31, hi = (t>>5)&1, c/kp = (t>>6)&3
    const int sl    = t & 31;
    const int chunk = 2 * ((t >> 6) & 3) + ((t >> 5) & 1);
    const bf16* kbase = qkv + (size_t)(b * 2048 + sl) * 3072 + 1024 + h * 64 + chunk * 8;
    const bf16* vbase = Vt + (size_t)(bh * 64 + sl) * 2048 + chunk * 8;

    auto stage = [&](int tile, int bufi) {
        char* kd = (char*)&Ks[bufi][0] + t * 16;
        char* vd = (char*)&Vs[bufi][0] + t * 16;
        const bf16* ks0 = kbase + (size_t)(tile * 64) * 3072;
        const bf16* vs0 = vbase + tile * 64;
        __builtin_amdgcn_global_load_lds(AS1(ks0),                   AS3(kd),        16, 0, 0);
        __builtin_amdgcn_global_load_lds(AS1(ks0 + (size_t)32*3072), AS3(kd + 4096), 16, 0, 0);
        __builtin_amdgcn_global_load_lds(AS1(vs0),                   AS3(vd),        16, 0, 0);
        __builtin_amdgcn_global_load_lds(AS1(vs0 + (size_t)32*2048), AS3(vd + 4096), 16, 0, 0);
    };

    stage(0, 0);

    v16f o0 = {}, o1 = {};
    float lsum = 0.f;
    const int kfoff = wk * 2048 + lane * 8;   // K fragment base (elems)
    const int vb0   = wk * 1024 + lane * 8;   // V fragment base (elems)

    for (int tile = 0; tile < T; ++tile) {
        const int buf = tile & 1;
        __syncthreads();                 // staging of `tile` complete; prior reads done
        if (tile + 1 < T) stage(tile + 1, buf ^ 1);

        const int m_ = 2 * tile + wk;
        if (m_ <= ndiag) {               // skip fully-masked half-tiles
            const bf16* Kb = &Ks[buf][0];
            const bf16* Vb = &Vs[buf][0];

            // QK^T swapped: lane q = l31, k-rows = 32wk + crow(r,hi)
            v16f s = {};
#pragma unroll
            for (int c = 0; c < 4; ++c)
                s = mfma32(*(const v8s*)(Kb + kfoff + c * 512), qf[c], s);

            v8s paE, paO;
            softpack(s, tile * 64 + 32 * wk, qg, m_ == ndiag, hi, lsum, paE, paO);

            // PV: fragment-linear V reads, all offsets immediate
            o0 = mfma32(paE, *(const v8s*)(Vb + vb0),            o0);
            o1 = mfma32(paE, *(const v8s*)(Vb + vb0 + 4 * 512),  o1);
            o0 = mfma32(paO, *(const v8s*)(Vb + vb0 + 512),      o0);
            o1 = mfma32(paO, *(const v8s*)(Vb + vb0 + 5 * 512),  o1);
        }
    }

    // cross-wk combine: wk=1 publishes partial O (swizzled f32x4) + lsum
    __syncthreads();
    float* Rp = (float*)&Ks[0][0];       // 16 KB: 2 q-halves x 64 lanes x 32 f32
    float* Lp = (float*)&Vs[0][0];       // 512 B lsum
    if (wk) {
        float* R = Rp + wq * 2048 + lane * 32;
#pragma unroll
        for (int j = 0; j < 4; ++j) {
            v4f a = { o0[4*j], o0[4*j+1], o0[4*j+2], o0[4*j+3] };
            ((v4f*)R)[j ^ (lane & 7)] = a;
        }
#pragma unroll
        for (int j = 0; j < 4; ++j) {
            v4f a = { o1[4*j], o1[4*j+1], o1[4*j+2], o1[4*j+3] };
            ((v4f*)R)[(4 + j) ^ (lane & 7)] = a;
        }
        Lp[wq * 64 + lane] = lsum;
    }
    __syncthreads();
    if (!wk) {
        const float* R = Rp + wq * 2048 + lane * 32;
#pragma unroll
        for (int j = 0; j < 4; ++j) {
            v4f a = ((const v4f*)R)[j ^ (lane & 7)];
#pragma unroll
            for (int e = 0; e < 4; ++e) o0[4*j + e] += a[e];
        }
#pragma unroll
        for (int j = 0; j < 4; ++j) {
            v4f a = ((const v4f*)R)[(4 + j) ^ (lane & 7)];
#pragma unroll
            for (int e = 0; e < 4; ++e) o1[4*j + e] += a[e];
        }
        lsum += Lp[wq * 64 + lane];
        const float lt = lsum + __shfl_xor(lsum, 32);

        // write attention output into the dead V-third of qkv (cols 2048+)
        bf16* dst0 = qkv + (size_t)(b * 2048 + rowq) * 3072 + 2048 + h * 64 + l31;
#pragma unroll
        for (int r = 0; r < 16; ++r) {
            const int q = (r & 3) + 8 * (r >> 2) + 4 * hi;   // O row for this reg
            const float rs  = fmaxf(__shfl(lt, q), 1e-30f);
            const float inv = 1.0f / rs;
            bf16* dst = dst0 + (size_t)q * 3072;
            dst[0]  = __float2bfloat16(o0[r] * inv);
            dst[32] = __float2bfloat16(o1[r] * inv);
        }
    }
}

extern "C" void kernel_launch(void* const* d_in, const int* in_sizes, int n_in,
                              void* d_out, int out_size, void* d_ws, size_t ws_size,
                              hipStream_t stream)
{
    (void)in_sizes; (void)n_in; (void)out_size; (void)ws_size;
    const float* x     = (const float*)d_in[0];
    const float* w_in  = (const float*)d_in[1];
    const float* b_in  = (const float*)d_in[2];
    const float* w_out = (const float*)d_in[3];
    const float* b_out = (const float*)d_in[4];
    float* out = (float*)d_out;   // fp32 output [4096][1024]

    bf16* ws     = (bf16*)d_ws;
    bf16* xb     = ws;                           // [4096][1024]   8.4 MB
    bf16* w_inb  = xb     + (size_t)4096 * 1024; // [3072][1024]   6.3 MB
    bf16* w_outb = w_inb  + (size_t)3072 * 1024; // [1024][1024]   2.1 MB
    bf16* qkv    = w_outb + (size_t)1024 * 1024; // [4096][3072]  25.2 MB
    bf16* vt     = (bf16*)d_out;                 // [32*64][2048] scratch in d_out
                                                 // (dead before final GEMM writes out)

    cvt_all<<<8192, 256, 0, stream>>>(x, w_in, w_out, xb, w_inb, w_outb);

    // QKV projection: x[4096,1024] @ w_in^T + b_in -> qkv (128x128, BK=32, dbuf)
    gemm_bt<4><<<dim3(24, 32), dim3(256), 0, stream>>>(xb, w_inb, b_in, qkv, nullptr,
                                                       3072, 1024, 1024);
    // V -> Vt[bh][d][s]
    vtrans<<<dim3(32, 32), dim3(256), 0, stream>>>(qkv, vt);
    // causal flash attention (4 waves: 2 q-halves x 2 k-halves, fragment-ordered LDS)
    attn<<<1024, 256, 0, stream>>>(qkv, vt);
    // output projection -> fp32 d_out (128x64 tiles: 512 blocks = 2/CU)
    gemm_bt<2><<<dim3(16, 32), dim3(256), 0, stream>>>(qkv + 2048, w_outb, b_out, nullptr,
                                                       out, 1024, 1024, 3072);
}

// Round 4
// 187.250 us; speedup vs baseline: 1.0564x; 1.0513x over previous
//
#include <hip/hip_runtime.h>
#include <hip/hip_bf16.h>
#include <cmath>

typedef __hip_bfloat16 bf16;
typedef short v8s __attribute__((ext_vector_type(8)));   // 8 x bf16 bits
typedef short v4s __attribute__((ext_vector_type(4)));   // 4 x bf16 bits
typedef float v4f __attribute__((ext_vector_type(4)));
typedef float v16f __attribute__((ext_vector_type(16)));
typedef unsigned v4u __attribute__((ext_vector_type(4)));

#define AS1(p) ((__attribute__((address_space(1))) void*)(p))
#define AS3(p) ((__attribute__((address_space(3))) void*)(p))

__device__ __forceinline__ v4f mfma_bf16(v8s a, v8s b, v4f c) {
    return __builtin_amdgcn_mfma_f32_16x16x32_bf16(a, b, c, 0, 0, 0);
}
__device__ __forceinline__ v16f mfma32(v8s a, v8s b, v16f c) {
    return __builtin_amdgcn_mfma_f32_32x32x16_bf16(a, b, c, 0, 0, 0);
}

__device__ __forceinline__ short bf16_bits(float f) {
    return __builtin_bit_cast(short, __float2bfloat16(f));
}

__device__ __forceinline__ v8s pack4(unsigned a, unsigned b, unsigned c, unsigned d) {
    v4u u = {a, b, c, d};
    return __builtin_bit_cast(v8s, u);
}

// fused fp32 -> bf16 for x, w_in, w_out (float4 granularity)
__global__ __launch_bounds__(256)
void cvt_all(const float* __restrict__ x, const float* __restrict__ w_in,
             const float* __restrict__ w_out, bf16* __restrict__ xb,
             bf16* __restrict__ wib, bf16* __restrict__ wob)
{
    const int i = blockIdx.x * 256 + threadIdx.x;   // 0 .. 2097151
    const float* src; bf16* dst; int j;
    if (i < 1048576)      { src = x;     dst = xb;  j = i; }
    else if (i < 1835008) { src = w_in;  dst = wib; j = i - 1048576; }
    else                  { src = w_out; dst = wob; j = i - 1835008; }
    const float4 v = ((const float4*)src)[j];
    v4s p;
    p.x = bf16_bits(v.x); p.y = bf16_bits(v.y);
    p.z = bf16_bits(v.z); p.w = bf16_bits(v.w);
    ((v4s*)dst)[j] = p;
}

// C[m,n] = sum_k A[m,k] * Bt[n,k] + bias[n].  Tile: 128 x (NF*32), BK=32,
// double-buffered global_load_lds, XOR-4 swizzle (proven K-loop math, unchanged).
// Round-4 changes:
//  * 8 waves (512 thr), 4x2 wave grid (wm=32 rows, wn=NF*16 cols): 24 waves/CU
//    for gemm1 (was 12) to hide the per-iteration vmcnt(0)+barrier drain.
//  * XCD-contiguous block swizzle (T1): each XCD L2 keeps a 4-row A-panel slice.
//  * V-fusion: blocks with n0>=2048 (gemm1's V third) write transposed
//    Vt[(b*16+h)*64+d][s] directly (8-B v4s stores) -> vtrans kernel deleted.
template<int NF>
__global__ __launch_bounds__(512, 4)
void gemm_bt(const bf16* __restrict__ A, const bf16* __restrict__ Bt,
             const float* __restrict__ bias, bf16* __restrict__ C,
             float* __restrict__ Cf, bf16* __restrict__ VtOut,
             int N, int K, int lda)
{
    constexpr int BN = NF * 32;
    __shared__ __align__(16) bf16 As[2][128 * 32];
    __shared__ __align__(16) bf16 Bs[2][BN * 32];

    const int t    = threadIdx.x;        // 0..511
    const int lane = t & 63;
    const int w    = t >> 6;             // 0..7
    const int l16  = lane & 15;
    const int quad = lane >> 4;

    // XCD-contiguous swizzle: nwg divisible by 8; XCD k gets a contiguous
    // 4-row (by) band of the tile grid -> A-slice ~1MB resident in its L2.
    const int nwg  = gridDim.x * gridDim.y;
    const int orig = blockIdx.y * gridDim.x + blockIdx.x;
    const int swz  = (orig & 7) * (nwg >> 3) + (orig >> 3);
    const int m0   = (swz / gridDim.x) * 128;
    const int n0   = (swz % gridDim.x) * BN;

    const int wm   = (w & 3) * 32;            // 4 m-chunks of 32 rows
    const int wn   = (w >> 2) * (NF * 16);    // 2 n-chunks of NF*16 cols

    const v4f zf = {0.f, 0.f, 0.f, 0.f};
    v4f acc[2][NF];
#pragma unroll
    for (int i = 0; i < 2; ++i)
#pragma unroll
        for (int j = 0; j < NF; ++j) acc[i][j] = zf;

    // staging: thread t loads 16B; row sr = t>>2 (0..127),
    // global chunk g = (t&3) ^ ((sr>>1)&3)  (XOR-4 involution, read-side matched)
    const int sr = t >> 2;
    const int g  = ((t & 3) ^ ((sr >> 1) & 3)) * 8;
    const bf16* gA = A  + (size_t)(m0 + sr) * lda + g;
    const bf16* gB = Bt + (size_t)(n0 + sr) * K + g;

    auto stage = [&](int kt, int buf) {
        const int k0 = kt * 32;
        __builtin_amdgcn_global_load_lds(AS1(gA + k0), AS3((char*)&As[buf][0] + t * 16), 16, 0, 0);
        if (NF == 4 || t < 256)   // B has BN rows; wave-uniform guard
            __builtin_amdgcn_global_load_lds(AS1(gB + k0), AS3((char*)&Bs[buf][0] + t * 16), 16, 0, 0);
    };

    stage(0, 0);
    const int KT = K >> 5;
    const int xs = ((l16 >> 1) & 3) * 8;   // read-side chunk swizzle
    for (int kt = 0; kt < KT; ++kt) {
        const int buf = kt & 1;
        __syncthreads();                    // buf staged; prev reads of buf^1 done
        if (kt + 1 < KT) stage(kt + 1, buf ^ 1);

        v8s af[2], bfr[NF];
#pragma unroll
        for (int mi = 0; mi < 2; ++mi)
            af[mi] = *(const v8s*)(&As[buf][0] + (wm + mi * 16 + l16) * 32
                                   + ((quad * 8) ^ xs));
#pragma unroll
        for (int ni = 0; ni < NF; ++ni)
            bfr[ni] = *(const v8s*)(&Bs[buf][0] + (wn + ni * 16 + l16) * 32
                                    + ((quad * 8) ^ xs));
#pragma unroll
        for (int mi = 0; mi < 2; ++mi)
#pragma unroll
            for (int ni = 0; ni < NF; ++ni)
                acc[mi][ni] = mfma_bf16(af[mi], bfr[ni], acc[mi][ni]);
    }

    // epilogue: D[row=quad*4+r][col=l16] per 16x16 tile (m91-verified layout)
    if (VtOut != nullptr && n0 >= 2048) {
        // V third -> transposed Vt[(b*16+h)*64+d][s], 8-B aligned v4s stores
        const int bb   = m0 >> 11;            // batch (m0 multiple of 128)
        const int srow = (m0 & 2047) + wm;    // s base for this wave
#pragma unroll
        for (int ni = 0; ni < NF; ++ni) {
            const int col = n0 + wn + ni * 16 + l16;
            const int hd  = col - 2048;       // h*64 + d
            const float bv = bias[col];
            bf16* vdst = VtOut + (size_t)(bb * 1024 + hd) * 2048 + srow;
#pragma unroll
            for (int mi = 0; mi < 2; ++mi) {
                v4s p;
#pragma unroll
                for (int r = 0; r < 4; ++r)
                    p[r] = bf16_bits(acc[mi][ni][r] + bv);
                *(v4s*)(vdst + mi * 16 + quad * 4) = p;
            }
        }
    } else {
#pragma unroll
        for (int ni = 0; ni < NF; ++ni) {
            const int col = n0 + wn + ni * 16 + l16;
            const float bv = bias[col];
#pragma unroll
            for (int mi = 0; mi < 2; ++mi) {
#pragma unroll
                for (int r = 0; r < 4; ++r) {
                    const int row = m0 + wm + mi * 16 + quad * 4 + r;
                    const float fv = acc[mi][ni][r] + bv;
                    if (Cf) Cf[(size_t)row * N + col] = fv;
                    else    C [(size_t)row * N + col] = __float2bfloat16(fv);
                }
            }
        }
    }
}

// Causal flash attention: 64 q-rows/block, 4 waves = (2 q-halves) x (2 k-halves),
// 32x32x16 MFMA, swapped QK^T (S^T = K*Q^T), in-register softmax (T12:
// cvt_pk_bf16 + permlane32_swap), static-max p = exp(s/8 - 14).
// FRAGMENT-ORDERED LDS (zero bank conflicts by construction).
// Block-id remap: XCD k owns heads bh in [4k,4k+4) entirely -> K/V working set
// 2MB fits the 4MB per-XCD L2; heavy q-tiles dispatched first within each XCD.
#define M_STATIC 14.0f

__device__ __forceinline__ void softpack(v16f s, int kg0, int qg, bool mask, int hi,
                                         float& lsum, v8s& paE, v8s& paO)
{
    float p[16];
#pragma unroll
    for (int r = 0; r < 16; ++r) {
        float pv = __expf(fmaf(s[r], 0.125f, -M_STATIC));
        if (mask) {
            const int kg = kg0 + (r & 3) + 8 * (r >> 2) + 4 * hi;
            if (kg > qg) pv = 0.f;
        }
        lsum += pv;
        p[r] = pv;
    }
    unsigned P0[4], P1[4];
#pragma unroll
    for (int m = 0; m < 4; ++m) {
        asm("v_cvt_pk_bf16_f32 %0, %1, %2" : "=v"(P0[m]) : "v"(p[4 * m]),     "v"(p[4 * m + 1]));
        asm("v_cvt_pk_bf16_f32 %0, %1, %2" : "=v"(P1[m]) : "v"(p[4 * m + 2]), "v"(p[4 * m + 3]));
    }
    auto sA = __builtin_amdgcn_permlane32_swap(P0[0], P0[1], false, false);
    auto sB = __builtin_amdgcn_permlane32_swap(P1[0], P1[1], false, false);
    auto sC = __builtin_amdgcn_permlane32_swap(P0[2], P0[3], false, false);
    auto sD = __builtin_amdgcn_permlane32_swap(P1[2], P1[3], false, false);
    paE = pack4(sA[0], sB[0], sA[1], sB[1]);
    paO = pack4(sC[0], sD[0], sC[1], sD[1]);
}

__global__ __launch_bounds__(256, 4)
void attn(bf16* __restrict__ qkv, const bf16* __restrict__ Vt)
{
    __shared__ __align__(16) bf16 Ks[2][64 * 64];   // fragment-ordered, 8KB each
    __shared__ __align__(16) bf16 Vs[2][64 * 64];

    const int t    = threadIdx.x;        // 0..255
    const int lane = t & 63;
    const int w    = t >> 6;             // 0..3
    const int wq   = w >> 1;             // q-half
    const int wk   = w & 1;              // k-half
    const int l31  = lane & 31;
    const int hi   = lane >> 5;
    const int id   = blockIdx.x;         // 1024 blocks
    // XCD-local head mapping: xcd = id&7 owns bh = 4*(id&7) + (j&3); heavy-first qb
    const int j    = id >> 3;
    const int bh   = (id & 7) * 4 + (j & 3);
    const int qb   = 31 - (j >> 2);
    const int b = bh >> 4, h = bh & 15;
    const int T = qb + 1;                // 64-wide k-tiles to the causal frontier
    const int rowq  = qb * 64 + wq * 32; // wave's first q-row
    const int qg    = rowq + l31;        // this lane's q row
    const int ndiag = 2 * qb + wq;       // wave diagonal index (32-units)

    // Q fragments (B-operand): qf[c] = Q[qg][16c + 8hi + j]
    v8s qf[4];
    {
        const bf16* Qb = qkv + (size_t)(b * 2048 + qg) * 3072 + h * 64 + hi * 8;
#pragma unroll
        for (int c = 0; c < 4; ++c) qf[c] = *(const v8s*)(Qb + c * 16);
    }

    // fragment-order staging: thread t owns slots t and t+256.
    // slot decode: row-in-32 = t&31, hi = (t>>5)&1, c/kp = (t>>6)&3
    const int sl    = t & 31;
    const int chunk = 2 * ((t >> 6) & 3) + ((t >> 5) & 1);
    const bf16* kbase = qkv + (size_t)(b * 2048 + sl) * 3072 + 1024 + h * 64 + chunk * 8;
    const bf16* vbase = Vt + (size_t)(bh * 64 + sl) * 2048 + chunk * 8;

    auto stage = [&](int tile, int bufi) {
        char* kd = (char*)&Ks[bufi][0] + t * 16;
        char* vd = (char*)&Vs[bufi][0] + t * 16;
        const bf16* ks0 = kbase + (size_t)(tile * 64) * 3072;
        const bf16* vs0 = vbase + tile * 64;
        __builtin_amdgcn_global_load_lds(AS1(ks0),                   AS3(kd),        16, 0, 0);
        __builtin_amdgcn_global_load_lds(AS1(ks0 + (size_t)32*3072), AS3(kd + 4096), 16, 0, 0);
        __builtin_amdgcn_global_load_lds(AS1(vs0),                   AS3(vd),        16, 0, 0);
        __builtin_amdgcn_global_load_lds(AS1(vs0 + (size_t)32*2048), AS3(vd + 4096), 16, 0, 0);
    };

    stage(0, 0);

    v16f o0 = {}, o1 = {};
    float lsum = 0.f;
    const int kfoff = wk * 2048 + lane * 8;   // K fragment base (elems)
    const int vb0   = wk * 1024 + lane * 8;   // V fragment base (elems)

    for (int tile = 0; tile < T; ++tile) {
        const int buf = tile & 1;
        __syncthreads();                 // staging of `tile` complete; prior reads done
        if (tile + 1 < T) stage(tile + 1, buf ^ 1);

        const int m_ = 2 * tile + wk;
        if (m_ <= ndiag) {               // skip fully-masked half-tiles
            const bf16* Kb = &Ks[buf][0];
            const bf16* Vb = &Vs[buf][0];

            // QK^T swapped: lane q = l31, k-rows = 32wk + crow(r,hi)
            v16f s = {};
#pragma unroll
            for (int c = 0; c < 4; ++c)
                s = mfma32(*(const v8s*)(Kb + kfoff + c * 512), qf[c], s);

            v8s paE, paO;
            softpack(s, tile * 64 + 32 * wk, qg, m_ == ndiag, hi, lsum, paE, paO);

            // PV: fragment-linear V reads, all offsets immediate
            o0 = mfma32(paE, *(const v8s*)(Vb + vb0),            o0);
            o1 = mfma32(paE, *(const v8s*)(Vb + vb0 + 4 * 512),  o1);
            o0 = mfma32(paO, *(const v8s*)(Vb + vb0 + 512),      o0);
            o1 = mfma32(paO, *(const v8s*)(Vb + vb0 + 5 * 512),  o1);
        }
    }

    // cross-wk combine: wk=1 publishes partial O (swizzled f32x4) + lsum
    __syncthreads();
    float* Rp = (float*)&Ks[0][0];       // 16 KB: 2 q-halves x 64 lanes x 32 f32
    float* Lp = (float*)&Vs[0][0];       // 512 B lsum
    if (wk) {
        float* R = Rp + wq * 2048 + lane * 32;
#pragma unroll
        for (int j2 = 0; j2 < 4; ++j2) {
            v4f a = { o0[4*j2], o0[4*j2+1], o0[4*j2+2], o0[4*j2+3] };
            ((v4f*)R)[j2 ^ (lane & 7)] = a;
        }
#pragma unroll
        for (int j2 = 0; j2 < 4; ++j2) {
            v4f a = { o1[4*j2], o1[4*j2+1], o1[4*j2+2], o1[4*j2+3] };
            ((v4f*)R)[(4 + j2) ^ (lane & 7)] = a;
        }
        Lp[wq * 64 + lane] = lsum;
    }
    __syncthreads();
    if (!wk) {
        const float* R = Rp + wq * 2048 + lane * 32;
#pragma unroll
        for (int j2 = 0; j2 < 4; ++j2) {
            v4f a = ((const v4f*)R)[j2 ^ (lane & 7)];
#pragma unroll
            for (int e = 0; e < 4; ++e) o0[4*j2 + e] += a[e];
        }
#pragma unroll
        for (int j2 = 0; j2 < 4; ++j2) {
            v4f a = ((const v4f*)R)[(4 + j2) ^ (lane & 7)];
#pragma unroll
            for (int e = 0; e < 4; ++e) o1[4*j2 + e] += a[e];
        }
        lsum += Lp[wq * 64 + lane];
        const float lt = lsum + __shfl_xor(lsum, 32);

        // write attention output into the dead V-third of qkv (cols 2048+)
        bf16* dst0 = qkv + (size_t)(b * 2048 + rowq) * 3072 + 2048 + h * 64 + l31;
#pragma unroll
        for (int r = 0; r < 16; ++r) {
            const int q = (r & 3) + 8 * (r >> 2) + 4 * hi;   // O row for this reg
            const float rs  = fmaxf(__shfl(lt, q), 1e-30f);
            const float inv = 1.0f / rs;
            bf16* dst = dst0 + (size_t)q * 3072;
            dst[0]  = __float2bfloat16(o0[r] * inv);
            dst[32] = __float2bfloat16(o1[r] * inv);
        }
    }
}

extern "C" void kernel_launch(void* const* d_in, const int* in_sizes, int n_in,
                              void* d_out, int out_size, void* d_ws, size_t ws_size,
                              hipStream_t stream)
{
    (void)in_sizes; (void)n_in; (void)out_size; (void)ws_size;
    const float* x     = (const float*)d_in[0];
    const float* w_in  = (const float*)d_in[1];
    const float* b_in  = (const float*)d_in[2];
    const float* w_out = (const float*)d_in[3];
    const float* b_out = (const float*)d_in[4];
    float* out = (float*)d_out;   // fp32 output [4096][1024]

    bf16* ws     = (bf16*)d_ws;
    bf16* xb     = ws;                           // [4096][1024]   8.4 MB
    bf16* w_inb  = xb     + (size_t)4096 * 1024; // [3072][1024]   6.3 MB
    bf16* w_outb = w_inb  + (size_t)3072 * 1024; // [1024][1024]   2.1 MB
    bf16* qkv    = w_outb + (size_t)1024 * 1024; // [4096][3072]  25.2 MB
    bf16* vt     = (bf16*)d_out;                 // [32*64][2048] scratch in d_out
                                                 // (dead before final GEMM writes out)

    cvt_all<<<8192, 256, 0, stream>>>(x, w_in, w_out, xb, w_inb, w_outb);

    // QKV projection: x[4096,1024] @ w_in^T + b_in -> qkv; V third written
    // transposed straight into vt (fused vtrans). 8-wave blocks, XCD swizzle.
    gemm_bt<4><<<dim3(24, 32), dim3(512), 0, stream>>>(xb, w_inb, b_in, qkv, nullptr,
                                                       vt, 3072, 1024, 1024);
    // causal flash attention (4 waves: 2 q-halves x 2 k-halves, fragment-ordered LDS)
    attn<<<1024, 256, 0, stream>>>(qkv, vt);
    // output projection -> fp32 d_out
    gemm_bt<2><<<dim3(16, 32), dim3(512), 0, stream>>>(qkv + 2048, w_outb, b_out, nullptr,
                                                       out, nullptr, 1024, 1024, 3072);
}